// Round 1
// baseline (388.902 us; speedup 1.0000x reference)
//
#include <hip/hip_runtime.h>
#include <stdint.h>

// ---------- helpers ----------
__device__ inline float u2f(unsigned v){ union{unsigned u; float f;} c; c.u=v; return c.f; }
__device__ inline unsigned f2u(float f){ union{float f; unsigned u;} c; c.f=f; return c.u; }
__device__ inline unsigned short f2bf(float f){
  unsigned u = f2u(f);
  unsigned r = u + 0x7FFFu + ((u>>16)&1u);   // RNE
  return (unsigned short)(r>>16);
}
__device__ inline unsigned packbf2(float a, float b){
  return (unsigned)f2bf(a) | ((unsigned)f2bf(b)<<16);
}
__device__ inline float4 load_bf16x4(const unsigned short* p){
  uint2 u = *reinterpret_cast<const uint2*>(p);
  float4 r;
  r.x = u2f(u.x<<16); r.y = u2f(u.x & 0xFFFF0000u);
  r.z = u2f(u.y<<16); r.w = u2f(u.y & 0xFFFF0000u);
  return r;
}

// ---------- 1. weight transpose + bias concat ----------
__global__ void prep_w(const float* __restrict__ Wl, const float* __restrict__ Wr,
                       const float* __restrict__ bl, const float* __restrict__ br,
                       float* __restrict__ Wt, float* __restrict__ bcat){
  int idx = blockIdx.x*blockDim.x + threadIdx.x;
  if (idx < 512*128){
    int k = idx >> 9, j = idx & 511;
    Wt[idx] = (j < 256) ? Wl[j*128 + k] : Wr[(j-256)*128 + k];
  }
  if (idx < 512) bcat[idx] = (idx < 256) ? bl[idx] : br[idx-256];
}

// ---------- 2. fp32 GEMM: [n,128] x [128,512] -> xl (n,256) bf16, xr (n,256) bf16 ----------
__launch_bounds__(256)
__global__ void gemm_xlxr(const float* __restrict__ x, const float* __restrict__ Wt,
                          const float* __restrict__ bcat,
                          unsigned short* __restrict__ xl, unsigned short* __restrict__ xr,
                          int n){
  __shared__ __align__(16) float Xs[32][132];   // 32 rows x 128 k, pad to 132
  int t = threadIdx.x;
  int row0 = blockIdx.x * 32;
  // stage x tile (row-major, float4 loads/stores, conflict-free)
  #pragma unroll
  for (int i = 0; i < 4; ++i){
    int id = t + i*256;
    int row = id >> 5;
    int k4 = id & 31;
    float4 v = make_float4(0.f,0.f,0.f,0.f);
    int gr = row0 + row;
    if (gr < n) v = *reinterpret_cast<const float4*>(&x[(size_t)gr*128 + k4*4]);
    *reinterpret_cast<float4*>(&Xs[row][k4*4]) = v;
  }
  __syncthreads();

  int c0 = (t & 127) * 4;     // 4 output cols
  int rh = t >> 7;            // row half: 16 rows
  float acc[16][4];
  #pragma unroll
  for (int i=0;i<16;++i){
    #pragma unroll
    for (int j=0;j<4;++j) acc[i][j]=0.f;
  }

  for (int k = 0; k < 128; k += 4){
    float4 b0 = *reinterpret_cast<const float4*>(&Wt[(k+0)*512 + c0]);
    float4 b1 = *reinterpret_cast<const float4*>(&Wt[(k+1)*512 + c0]);
    float4 b2 = *reinterpret_cast<const float4*>(&Wt[(k+2)*512 + c0]);
    float4 b3 = *reinterpret_cast<const float4*>(&Wt[(k+3)*512 + c0]);
    #pragma unroll
    for (int i=0;i<16;++i){
      float4 a = *reinterpret_cast<const float4*>(&Xs[rh*16+i][k]);  // wave-uniform -> broadcast
      acc[i][0] += a.x*b0.x + a.y*b1.x + a.z*b2.x + a.w*b3.x;
      acc[i][1] += a.x*b0.y + a.y*b1.y + a.z*b2.y + a.w*b3.y;
      acc[i][2] += a.x*b0.z + a.y*b1.z + a.z*b2.z + a.w*b3.z;
      acc[i][3] += a.x*b0.w + a.y*b1.w + a.z*b2.w + a.w*b3.w;
    }
  }

  float4 bc = *reinterpret_cast<const float4*>(&bcat[c0]);
  #pragma unroll
  for (int i=0;i<16;++i){
    int gr = row0 + rh*16 + i;
    if (gr < n){
      float v0 = acc[i][0] + bc.x;
      float v1 = acc[i][1] + bc.y;
      float v2 = acc[i][2] + bc.z;
      float v3 = acc[i][3] + bc.w;
      uint2 o; o.x = packbf2(v0,v1); o.y = packbf2(v2,v3);
      if (c0 < 256) *reinterpret_cast<uint2*>(&xl[(size_t)gr*256 + c0])       = o;
      else          *reinterpret_cast<uint2*>(&xr[(size_t)gr*256 + (c0-256)]) = o;
    }
  }
}

// ---------- 3. histogram of dst ----------
__global__ void hist_dst(const int* __restrict__ ei, int E, int* __restrict__ counts){
  for (int e = blockIdx.x*blockDim.x + threadIdx.x; e < E; e += gridDim.x*blockDim.x)
    atomicAdd(&counts[ei[E + e]], 1);
}

// ---------- 4. segment offset allocation (wave scan + one atomic per wave) ----------
__global__ void alloc_offsets(const int* __restrict__ counts, int n, int* __restrict__ offs,
                              int* __restrict__ cursor, int* __restrict__ total){
  int i = blockIdx.x*blockDim.x + threadIdx.x;
  int lane = threadIdx.x & 63;
  int v = (i < n) ? counts[i] : 0;
  int incl = v;
  #pragma unroll
  for (int d = 1; d < 64; d <<= 1){
    int y = __shfl_up(incl, d);
    if (lane >= d) incl += y;
  }
  int wsum = __shfl(incl, 63);
  int base = 0;
  if (lane == 0) base = atomicAdd(total, wsum);
  base = __shfl(base, 0);
  if (i < n){ int ex = base + incl - v; offs[i] = ex; cursor[i] = ex; }
}

// ---------- 5. scatter edges into dst-grouped order ----------
__global__ void scatter_edges(const int* __restrict__ ei, int E,
                              int* __restrict__ cursor, int* __restrict__ ssrc){
  for (int e = blockIdx.x*blockDim.x + threadIdx.x; e < E; e += gridDim.x*blockDim.x){
    int s = ei[e], d = ei[E + e];
    int pos = atomicAdd(&cursor[d], 1);
    ssrc[pos] = s;
  }
}

// ---------- 6. per-node GATv2 attention with online softmax ----------
// wave per node; lanes 0-31 head 0, lanes 32-63 head 1; float4/lane over C=128.
__launch_bounds__(256)
__global__ void node_attn(const unsigned short* __restrict__ xl,
                          const unsigned short* __restrict__ xr,
                          const float* __restrict__ att, const float* __restrict__ bias,
                          const int* __restrict__ offs, const int* __restrict__ counts,
                          const int* __restrict__ ssrc,
                          float* __restrict__ out, int n){
  int wave = threadIdx.x >> 6;
  int lane = threadIdx.x & 63;
  int v = blockIdx.x*4 + wave;
  if (v >= n) return;
  int h = lane >> 5, q = lane & 31;
  int fbase = h*128 + q*4;

  float4 xr4 = load_bf16x4(&xr[(size_t)v*256 + fbase]);
  float4 at4 = *reinterpret_cast<const float4*>(&att[fbase]);

  float m = -1e30f, s = 0.f;
  float4 acc = make_float4(0.f,0.f,0.f,0.f);

  int e0 = offs[v];
  int e1 = e0 + counts[v];
  // e = e0-1 is the self loop (src = v)
  for (int e = e0 - 1; e < e1; ++e){
    int src = (e < e0) ? v : ssrc[e];
    float4 xl4 = load_bf16x4(&xl[(size_t)src*256 + fbase]);
    float t0 = xl4.x + xr4.x;  t0 = t0 > 0.f ? t0 : 0.2f*t0;
    float t1 = xl4.y + xr4.y;  t1 = t1 > 0.f ? t1 : 0.2f*t1;
    float t2 = xl4.z + xr4.z;  t2 = t2 > 0.f ? t2 : 0.2f*t2;
    float t3 = xl4.w + xr4.w;  t3 = t3 > 0.f ? t3 : 0.2f*t3;
    float part = at4.x*t0 + at4.y*t1 + at4.z*t2 + at4.w*t3;
    part += __shfl_xor(part, 1);
    part += __shfl_xor(part, 2);
    part += __shfl_xor(part, 4);
    part += __shfl_xor(part, 8);
    part += __shfl_xor(part, 16);       // per-head logit, uniform within each half-wave
    float nm = fmaxf(m, part);
    float f = __expf(m - nm);
    float p = __expf(part - nm);
    s = s*f + p;
    acc.x = acc.x*f + p*xl4.x;
    acc.y = acc.y*f + p*xl4.y;
    acc.z = acc.z*f + p*xl4.z;
    acc.w = acc.w*f + p*xl4.w;
    m = nm;
  }

  float inv = 1.f/s;
  float4 val = make_float4(acc.x*inv, acc.y*inv, acc.z*inv, acc.w*inv);
  // exchange with the other head (lane ^ 32) and mean
  float ox = __shfl_xor(val.x, 32);
  float oy = __shfl_xor(val.y, 32);
  float oz = __shfl_xor(val.z, 32);
  float ow = __shfl_xor(val.w, 32);
  if (h == 0){
    float4 bi = *reinterpret_cast<const float4*>(&bias[q*4]);
    float4 o;
    o.x = 0.5f*(val.x + ox) + bi.x;
    o.y = 0.5f*(val.y + oy) + bi.y;
    o.z = 0.5f*(val.z + oz) + bi.z;
    o.w = 0.5f*(val.w + ow) + bi.w;
    *reinterpret_cast<float4*>(&out[(size_t)v*128 + q*4]) = o;
  }
}

// ---------- 7. column sums for GraphNorm ----------
__global__ void col_reduce(const float* __restrict__ out, int n,
                           float* __restrict__ colsum, float* __restrict__ colsq){
  __shared__ float s1[256], s2[256];
  int t = threadIdx.x;
  int c = t & 127, half = t >> 7;
  float sum = 0.f, sq = 0.f;
  for (int r = blockIdx.x*2 + half; r < n; r += gridDim.x*2){
    float v = out[(size_t)r*128 + c];
    sum += v; sq += v*v;
  }
  s1[t] = sum; s2[t] = sq;
  __syncthreads();
  if (t < 128){
    atomicAdd(&colsum[c], s1[t] + s1[t+128]);
    atomicAdd(&colsq[c],  s2[t] + s2[t+128]);
  }
}

// ---------- 8. finalize stats ----------
__global__ void fin_stats(const float* __restrict__ colsum, const float* __restrict__ colsq,
                          const float* __restrict__ ms, float* __restrict__ stats, int n){
  int c = threadIdx.x;
  if (c < 128){
    float invn = 1.f/(float)n;
    float mu  = colsum[c]*invn;
    float ex2 = colsq[c]*invn;
    float mm  = ms[c];
    float var = ex2 - 2.f*mm*mu*mu + mm*mm*mu*mu;  // E[(out - mm*mu)^2]
    stats[c]     = mm*mu;                           // shift
    stats[128+c] = rsqrtf(var + 1e-5f);             // rstd
  }
}

// ---------- 9. normalize + ELU + residual (in place on d_out) ----------
__global__ void final_ew(float* __restrict__ out, const float* __restrict__ x,
                         const float* __restrict__ stats, const float* __restrict__ gw,
                         const float* __restrict__ gb, int n){
  int total = n*32;
  for (int i = blockIdx.x*blockDim.x + threadIdx.x; i < total; i += gridDim.x*blockDim.x){
    int c4 = i & 31;
    float4 o  = reinterpret_cast<float4*>(out)[i];
    float4 xv = reinterpret_cast<const float4*>(x)[i];
    float4 sh = reinterpret_cast<const float4*>(stats)[c4];
    float4 rs = reinterpret_cast<const float4*>(stats)[32 + c4];
    float4 w4 = reinterpret_cast<const float4*>(gw)[c4];
    float4 b4 = reinterpret_cast<const float4*>(gb)[c4];
    float y0 = w4.x*((o.x - sh.x)*rs.x) + b4.x;  y0 = y0 > 0.f ? y0 : expm1f(y0);
    float y1 = w4.y*((o.y - sh.y)*rs.y) + b4.y;  y1 = y1 > 0.f ? y1 : expm1f(y1);
    float y2 = w4.z*((o.z - sh.z)*rs.z) + b4.z;  y2 = y2 > 0.f ? y2 : expm1f(y2);
    float y3 = w4.w*((o.w - sh.w)*rs.w) + b4.w;  y3 = y3 > 0.f ? y3 : expm1f(y3);
    o.x = y0 + xv.x; o.y = y1 + xv.y; o.z = y2 + xv.z; o.w = y3 + xv.w;
    reinterpret_cast<float4*>(out)[i] = o;
  }
}

// ---------- launch ----------
extern "C" void kernel_launch(void* const* d_in, const int* in_sizes, int n_in,
                              void* d_out, int out_size, void* d_ws, size_t ws_size,
                              hipStream_t stream){
  const float* x    = (const float*)d_in[0];
  const int*   ei   = (const int*)  d_in[1];
  const float* Wl   = (const float*)d_in[2];
  const float* bl   = (const float*)d_in[3];
  const float* Wr   = (const float*)d_in[4];
  const float* br   = (const float*)d_in[5];
  const float* att  = (const float*)d_in[6];
  const float* bias = (const float*)d_in[7];
  const float* gw   = (const float*)d_in[8];
  const float* gb   = (const float*)d_in[9];
  const float* gms  = (const float*)d_in[10];
  int n = in_sizes[0] / 128;
  int E = in_sizes[1] / 2;
  float* outp = (float*)d_out;

  char* w = (char*)d_ws;
  size_t off = 0;
  auto alloc = [&](size_t bytes)->char*{
    char* p = w + off; off += (bytes + 255) & ~(size_t)255; return p;
  };
  unsigned short* xl  = (unsigned short*)alloc((size_t)n*256*2);
  unsigned short* xr  = (unsigned short*)alloc((size_t)n*256*2);
  float* Wt     = (float*)alloc(512*128*4);
  float* bcat   = (float*)alloc(512*4);
  int*   counts = (int*)  alloc((size_t)n*4);
  int*   offs   = (int*)  alloc((size_t)n*4);
  int*   cursor = (int*)  alloc((size_t)n*4);
  int*   total  = (int*)  alloc(4);
  int*   ssrc   = (int*)  alloc((size_t)E*4);
  float* colsum = (float*)alloc(128*4);
  float* colsq  = (float*)alloc(128*4);
  float* stats  = (float*)alloc(256*4);
  if (off > ws_size) return;   // workspace too small; fail loudly via wrong output

  hipMemsetAsync(counts, 0, (size_t)n*4, stream);
  hipMemsetAsync(total,  0, 4, stream);
  hipMemsetAsync(colsum, 0, 128*4, stream);
  hipMemsetAsync(colsq,  0, 128*4, stream);

  prep_w       <<<256, 256, 0, stream>>>(Wl, Wr, bl, br, Wt, bcat);
  gemm_xlxr    <<<(n+31)/32, 256, 0, stream>>>(x, Wt, bcat, xl, xr, n);
  hist_dst     <<<512, 256, 0, stream>>>(ei, E, counts);
  alloc_offsets<<<(n+255)/256, 256, 0, stream>>>(counts, n, offs, cursor, total);
  scatter_edges<<<512, 256, 0, stream>>>(ei, E, cursor, ssrc);
  node_attn    <<<(n+3)/4, 256, 0, stream>>>(xl, xr, att, bias, offs, counts, ssrc, outp, n);
  col_reduce   <<<256, 256, 0, stream>>>(outp, n, colsum, colsq);
  fin_stats    <<<1, 128, 0, stream>>>(colsum, colsq, gms, stats, n);
  final_ew     <<<2048, 256, 0, stream>>>(outp, x, stats, gw, gb, n);
}

// Round 2
// 323.794 us; speedup vs baseline: 1.2011x; 1.2011x over previous
//
#include <hip/hip_runtime.h>
#include <stdint.h>

typedef __attribute__((ext_vector_type(8))) short bf16x8;
typedef __attribute__((ext_vector_type(4))) float f32x4;

// ---------- helpers ----------
__device__ inline float u2f(unsigned v){ union{unsigned u; float f;} c; c.u=v; return c.f; }
__device__ inline unsigned f2u(float f){ union{float f; unsigned u;} c; c.f=f; return c.u; }
__device__ inline unsigned short f2bf(float f){
  unsigned u = f2u(f);
  unsigned r = u + 0x7FFFu + ((u>>16)&1u);   // RNE
  return (unsigned short)(r>>16);
}
__device__ inline unsigned packbf2(float a, float b){
  return (unsigned)f2bf(a) | ((unsigned)f2bf(b)<<16);
}
__device__ inline float4 load_bf16x4(const unsigned short* p){
  uint2 u = *reinterpret_cast<const uint2*>(p);
  float4 r;
  r.x = u2f(u.x<<16); r.y = u2f(u.x & 0xFFFF0000u);
  r.z = u2f(u.y<<16); r.w = u2f(u.y & 0xFFFF0000u);
  return r;
}

// ---------- 1. weight -> bf16 concat [512][128], bias concat ----------
__global__ void prep_w(const float* __restrict__ Wl, const float* __restrict__ Wr,
                       const float* __restrict__ bl, const float* __restrict__ br,
                       unsigned short* __restrict__ Wb, float* __restrict__ bcat){
  int idx = blockIdx.x*blockDim.x + threadIdx.x;
  if (idx < 512*128){
    int j = idx >> 7, k = idx & 127;
    float v = (j < 256) ? Wl[j*128 + k] : Wr[(j-256)*128 + k];
    Wb[idx] = f2bf(v);
  }
  if (idx < 512) bcat[idx] = (idx < 256) ? bl[idx] : br[idx-256];
}

// ---------- 2. bf16 MFMA GEMM: [n,128] x [128,512] -> xl,xr bf16 ----------
// block = 4 waves; tile 32 rows x 512 cols; wave w owns cols [w*128, w*128+128)
__launch_bounds__(256)
__global__ void gemm_mfma(const float* __restrict__ x, const unsigned short* __restrict__ Wb,
                          const float* __restrict__ bcat,
                          unsigned short* __restrict__ xl, unsigned short* __restrict__ xr,
                          int n){
  int wave = threadIdx.x >> 6, lane = threadIdx.x & 63;
  int row0 = blockIdx.x * 32;
  int ncol0 = wave * 128;
  int lrow = lane & 15, lkb = (lane >> 4) * 8;

  // A fragments: 2 m-tiles x 4 k-steps, each lane holds 8 bf16 (rows lrow, k = ks*32+lkb..+7)
  union { bf16x8 v; unsigned u[4]; } afr[2][4];
  #pragma unroll
  for (int mt = 0; mt < 2; ++mt){
    int row = row0 + mt*16 + lrow; if (row >= n) row = n-1;
    const float* xp = &x[(size_t)row*128];
    #pragma unroll
    for (int ks = 0; ks < 4; ++ks){
      float4 f0 = *reinterpret_cast<const float4*>(xp + ks*32 + lkb);
      float4 f1 = *reinterpret_cast<const float4*>(xp + ks*32 + lkb + 4);
      afr[mt][ks].u[0] = packbf2(f0.x, f0.y);
      afr[mt][ks].u[1] = packbf2(f0.z, f0.w);
      afr[mt][ks].u[2] = packbf2(f1.x, f1.y);
      afr[mt][ks].u[3] = packbf2(f1.z, f1.w);
    }
  }

  f32x4 acc[2][8];
  #pragma unroll
  for (int mt = 0; mt < 2; ++mt)
    #pragma unroll
    for (int nt = 0; nt < 8; ++nt) acc[mt][nt] = (f32x4){0.f,0.f,0.f,0.f};

  #pragma unroll
  for (int ks = 0; ks < 4; ++ks){
    #pragma unroll
    for (int nt = 0; nt < 8; ++nt){
      int col = ncol0 + nt*16 + lrow;               // Wb is [512][128] row-major = B^T
      union { bf16x8 v; uint4 u; } bfr;
      bfr.u = *reinterpret_cast<const uint4*>(&Wb[(size_t)col*128 + ks*32 + lkb]);
      acc[0][nt] = __builtin_amdgcn_mfma_f32_16x16x32_bf16(afr[0][ks].v, bfr.v, acc[0][nt], 0,0,0);
      acc[1][nt] = __builtin_amdgcn_mfma_f32_16x16x32_bf16(afr[1][ks].v, bfr.v, acc[1][nt], 0,0,0);
    }
  }

  // C/D layout: col = lane&15, row = (lane>>4)*4 + i
  #pragma unroll
  for (int mt = 0; mt < 2; ++mt){
    #pragma unroll
    for (int nt = 0; nt < 8; ++nt){
      int gc = ncol0 + nt*16 + lrow;
      float bi = bcat[gc];
      unsigned short* dst = (gc < 256) ? xl : xr;
      int cc = (gc < 256) ? gc : gc - 256;
      #pragma unroll
      for (int i = 0; i < 4; ++i){
        int row = row0 + mt*16 + (lane>>4)*4 + i;
        if (row < n) dst[(size_t)row*256 + cc] = f2bf(acc[mt][nt][i] + bi);
      }
    }
  }
}

// ---------- 3. histogram of dst ----------
__global__ void hist_dst(const int* __restrict__ ei, int E, int* __restrict__ counts){
  for (int e = blockIdx.x*blockDim.x + threadIdx.x; e < E; e += gridDim.x*blockDim.x)
    atomicAdd(&counts[ei[E + e]], 1);
}

// ---------- 4. segment offset allocation ----------
__global__ void alloc_offsets(const int* __restrict__ counts, int n, int* __restrict__ offs,
                              int* __restrict__ cursor, int* __restrict__ total){
  int i = blockIdx.x*blockDim.x + threadIdx.x;
  int lane = threadIdx.x & 63;
  int v = (i < n) ? counts[i] : 0;
  int incl = v;
  #pragma unroll
  for (int d = 1; d < 64; d <<= 1){
    int y = __shfl_up(incl, d);
    if (lane >= d) incl += y;
  }
  int wsum = __shfl(incl, 63);
  int base = 0;
  if (lane == 0) base = atomicAdd(total, wsum);
  base = __shfl(base, 0);
  if (i < n){ int ex = base + incl - v; offs[i] = ex; cursor[i] = ex; }
}

// ---------- 5. scatter edges into dst-grouped order ----------
__global__ void scatter_edges(const int* __restrict__ ei, int E,
                              int* __restrict__ cursor, int* __restrict__ ssrc){
  for (int e = blockIdx.x*blockDim.x + threadIdx.x; e < E; e += gridDim.x*blockDim.x){
    int s = ei[e], d = ei[E + e];
    int pos = atomicAdd(&cursor[d], 1);
    ssrc[pos] = s;
  }
}

// ---------- 6. per-node GATv2 attention, 4-edge pipelined online softmax ----------
__launch_bounds__(256)
__global__ void node_attn(const unsigned short* __restrict__ xl,
                          const unsigned short* __restrict__ xr,
                          const float* __restrict__ att, const float* __restrict__ bias,
                          const int* __restrict__ offs, const int* __restrict__ counts,
                          const int* __restrict__ ssrc,
                          float* __restrict__ out, int n){
  int wave = threadIdx.x >> 6;
  int lane = threadIdx.x & 63;
  int v = blockIdx.x*4 + wave;
  if (v >= n) return;
  int h = lane >> 5, q = lane & 31;
  int fbase = h*128 + q*4;

  float4 xr4 = load_bf16x4(&xr[(size_t)v*256 + fbase]);
  float4 at4 = *reinterpret_cast<const float4*>(&att[fbase]);

  // self loop (src = v) initializes the online state
  float4 as = load_bf16x4(&xl[(size_t)v*256 + fbase]);
  float t0 = as.x + xr4.x;  t0 = t0 > 0.f ? t0 : 0.2f*t0;
  float t1 = as.y + xr4.y;  t1 = t1 > 0.f ? t1 : 0.2f*t1;
  float t2 = as.z + xr4.z;  t2 = t2 > 0.f ? t2 : 0.2f*t2;
  float t3 = as.w + xr4.w;  t3 = t3 > 0.f ? t3 : 0.2f*t3;
  float ds = at4.x*t0 + at4.y*t1 + at4.z*t2 + at4.w*t3;
  ds += __shfl_xor(ds, 1);  ds += __shfl_xor(ds, 2);  ds += __shfl_xor(ds, 4);
  ds += __shfl_xor(ds, 8);  ds += __shfl_xor(ds, 16);
  float m = ds, s = 1.f;
  float4 acc = as;

  int e0 = offs[v];
  int e1 = e0 + counts[v];
  int e = e0;
  while (e < e1){
    int cnt = e1 - e; if (cnt > 64) cnt = 64;
    int idx = e + lane; if (idx >= e1) idx = e1 - 1;
    int batch = ssrc[idx];                      // 64 coalesced src ids
    for (int j = 0; j < cnt; j += 4){
      int s0 = __shfl(batch, j);
      int s1 = __shfl(batch, j+1);
      int s2 = __shfl(batch, j+2);
      int s3 = __shfl(batch, j+3);
      float4 a0 = load_bf16x4(&xl[(size_t)s0*256 + fbase]);
      float4 a1 = load_bf16x4(&xl[(size_t)s1*256 + fbase]);
      float4 a2 = load_bf16x4(&xl[(size_t)s2*256 + fbase]);
      float4 a3 = load_bf16x4(&xl[(size_t)s3*256 + fbase]);

      float u0,u1,u2,u3, d0,d1,d2,d3;
      u0 = a0.x + xr4.x; u0 = u0 > 0.f ? u0 : 0.2f*u0; d0  = at4.x*u0;
      u0 = a0.y + xr4.y; u0 = u0 > 0.f ? u0 : 0.2f*u0; d0 += at4.y*u0;
      u0 = a0.z + xr4.z; u0 = u0 > 0.f ? u0 : 0.2f*u0; d0 += at4.z*u0;
      u0 = a0.w + xr4.w; u0 = u0 > 0.f ? u0 : 0.2f*u0; d0 += at4.w*u0;
      u1 = a1.x + xr4.x; u1 = u1 > 0.f ? u1 : 0.2f*u1; d1  = at4.x*u1;
      u1 = a1.y + xr4.y; u1 = u1 > 0.f ? u1 : 0.2f*u1; d1 += at4.y*u1;
      u1 = a1.z + xr4.z; u1 = u1 > 0.f ? u1 : 0.2f*u1; d1 += at4.z*u1;
      u1 = a1.w + xr4.w; u1 = u1 > 0.f ? u1 : 0.2f*u1; d1 += at4.w*u1;
      u2 = a2.x + xr4.x; u2 = u2 > 0.f ? u2 : 0.2f*u2; d2  = at4.x*u2;
      u2 = a2.y + xr4.y; u2 = u2 > 0.f ? u2 : 0.2f*u2; d2 += at4.y*u2;
      u2 = a2.z + xr4.z; u2 = u2 > 0.f ? u2 : 0.2f*u2; d2 += at4.z*u2;
      u2 = a2.w + xr4.w; u2 = u2 > 0.f ? u2 : 0.2f*u2; d2 += at4.w*u2;
      u3 = a3.x + xr4.x; u3 = u3 > 0.f ? u3 : 0.2f*u3; d3  = at4.x*u3;
      u3 = a3.y + xr4.y; u3 = u3 > 0.f ? u3 : 0.2f*u3; d3 += at4.y*u3;
      u3 = a3.z + xr4.z; u3 = u3 > 0.f ? u3 : 0.2f*u3; d3 += at4.z*u3;
      u3 = a3.w + xr4.w; u3 = u3 > 0.f ? u3 : 0.2f*u3; d3 += at4.w*u3;

      // 4 interleaved half-wave reductions
      d0 += __shfl_xor(d0, 1);  d1 += __shfl_xor(d1, 1);
      d2 += __shfl_xor(d2, 1);  d3 += __shfl_xor(d3, 1);
      d0 += __shfl_xor(d0, 2);  d1 += __shfl_xor(d1, 2);
      d2 += __shfl_xor(d2, 2);  d3 += __shfl_xor(d3, 2);
      d0 += __shfl_xor(d0, 4);  d1 += __shfl_xor(d1, 4);
      d2 += __shfl_xor(d2, 4);  d3 += __shfl_xor(d3, 4);
      d0 += __shfl_xor(d0, 8);  d1 += __shfl_xor(d1, 8);
      d2 += __shfl_xor(d2, 8);  d3 += __shfl_xor(d3, 8);
      d0 += __shfl_xor(d0, 16); d1 += __shfl_xor(d1, 16);
      d2 += __shfl_xor(d2, 16); d3 += __shfl_xor(d3, 16);

      if (j+1 >= cnt) d1 = -1e30f;
      if (j+2 >= cnt) d2 = -1e30f;
      if (j+3 >= cnt) d3 = -1e30f;

      // single batched online update
      float nm = fmaxf(m, fmaxf(fmaxf(d0,d1), fmaxf(d2,d3)));
      float f  = __expf(m - nm);
      float p0 = __expf(d0 - nm), p1 = __expf(d1 - nm);
      float p2 = __expf(d2 - nm), p3 = __expf(d3 - nm);
      s = s*f + ((p0+p1)+(p2+p3));
      acc.x = acc.x*f + p0*a0.x + p1*a1.x + p2*a2.x + p3*a3.x;
      acc.y = acc.y*f + p0*a0.y + p1*a1.y + p2*a2.y + p3*a3.y;
      acc.z = acc.z*f + p0*a0.z + p1*a1.z + p2*a2.z + p3*a3.z;
      acc.w = acc.w*f + p0*a0.w + p1*a1.w + p2*a2.w + p3*a3.w;
      m = nm;
    }
    e += cnt;
  }

  float inv = 1.f/s;
  float4 val = make_float4(acc.x*inv, acc.y*inv, acc.z*inv, acc.w*inv);
  float ox = __shfl_xor(val.x, 32);
  float oy = __shfl_xor(val.y, 32);
  float oz = __shfl_xor(val.z, 32);
  float ow = __shfl_xor(val.w, 32);
  if (h == 0){
    float4 bi = *reinterpret_cast<const float4*>(&bias[q*4]);
    float4 o;
    o.x = 0.5f*(val.x + ox) + bi.x;
    o.y = 0.5f*(val.y + oy) + bi.y;
    o.z = 0.5f*(val.z + oz) + bi.z;
    o.w = 0.5f*(val.w + ow) + bi.w;
    *reinterpret_cast<float4*>(&out[(size_t)v*128 + q*4]) = o;
  }
}

// ---------- 7. column sums for GraphNorm (float4) ----------
__global__ void col_reduce(const float* __restrict__ out, int n,
                           float* __restrict__ colsum, float* __restrict__ colsq){
  __shared__ float s1[256*4], s2[256*4];
  int t = threadIdx.x;
  int c4 = t & 31, rg = t >> 5;               // 32 float4-cols, 8 row groups
  float4 sum = make_float4(0,0,0,0), sq = make_float4(0,0,0,0);
  for (int r = blockIdx.x*8 + rg; r < n; r += gridDim.x*8){
    float4 v = reinterpret_cast<const float4*>(out)[(size_t)r*32 + c4];
    sum.x += v.x; sum.y += v.y; sum.z += v.z; sum.w += v.w;
    sq.x += v.x*v.x; sq.y += v.y*v.y; sq.z += v.z*v.z; sq.w += v.w*v.w;
  }
  reinterpret_cast<float4*>(s1)[t] = sum;
  reinterpret_cast<float4*>(s2)[t] = sq;
  __syncthreads();
  if (t < 32){
    #pragma unroll
    for (int g = 1; g < 8; ++g){
      float4 a = reinterpret_cast<float4*>(s1)[t + g*32];
      float4 b = reinterpret_cast<float4*>(s2)[t + g*32];
      sum.x += a.x; sum.y += a.y; sum.z += a.z; sum.w += a.w;
      sq.x  += b.x; sq.y  += b.y; sq.z  += b.z; sq.w  += b.w;
    }
    atomicAdd(&colsum[t*4+0], sum.x); atomicAdd(&colsum[t*4+1], sum.y);
    atomicAdd(&colsum[t*4+2], sum.z); atomicAdd(&colsum[t*4+3], sum.w);
    atomicAdd(&colsq[t*4+0], sq.x);  atomicAdd(&colsq[t*4+1], sq.y);
    atomicAdd(&colsq[t*4+2], sq.z);  atomicAdd(&colsq[t*4+3], sq.w);
  }
}

// ---------- 8. finalize stats ----------
__global__ void fin_stats(const float* __restrict__ colsum, const float* __restrict__ colsq,
                          const float* __restrict__ ms, float* __restrict__ stats, int n){
  int c = threadIdx.x;
  if (c < 128){
    float invn = 1.f/(float)n;
    float mu  = colsum[c]*invn;
    float ex2 = colsq[c]*invn;
    float mm  = ms[c];
    float var = ex2 - 2.f*mm*mu*mu + mm*mm*mu*mu;
    stats[c]     = mm*mu;
    stats[128+c] = rsqrtf(var + 1e-5f);
  }
}

// ---------- 9. normalize + ELU + residual ----------
__global__ void final_ew(float* __restrict__ out, const float* __restrict__ x,
                         const float* __restrict__ stats, const float* __restrict__ gw,
                         const float* __restrict__ gb, int n){
  int total = n*32;
  for (int i = blockIdx.x*blockDim.x + threadIdx.x; i < total; i += gridDim.x*blockDim.x){
    int c4 = i & 31;
    float4 o  = reinterpret_cast<float4*>(out)[i];
    float4 xv = reinterpret_cast<const float4*>(x)[i];
    float4 sh = reinterpret_cast<const float4*>(stats)[c4];
    float4 rs = reinterpret_cast<const float4*>(stats)[32 + c4];
    float4 w4 = reinterpret_cast<const float4*>(gw)[c4];
    float4 b4 = reinterpret_cast<const float4*>(gb)[c4];
    float y0 = w4.x*((o.x - sh.x)*rs.x) + b4.x;  y0 = y0 > 0.f ? y0 : expm1f(y0);
    float y1 = w4.y*((o.y - sh.y)*rs.y) + b4.y;  y1 = y1 > 0.f ? y1 : expm1f(y1);
    float y2 = w4.z*((o.z - sh.z)*rs.z) + b4.z;  y2 = y2 > 0.f ? y2 : expm1f(y2);
    float y3 = w4.w*((o.w - sh.w)*rs.w) + b4.w;  y3 = y3 > 0.f ? y3 : expm1f(y3);
    o.x = y0 + xv.x; o.y = y1 + xv.y; o.z = y2 + xv.z; o.w = y3 + xv.w;
    reinterpret_cast<float4*>(out)[i] = o;
  }
}

// ---------- launch ----------
extern "C" void kernel_launch(void* const* d_in, const int* in_sizes, int n_in,
                              void* d_out, int out_size, void* d_ws, size_t ws_size,
                              hipStream_t stream){
  const float* x    = (const float*)d_in[0];
  const int*   ei   = (const int*)  d_in[1];
  const float* Wl   = (const float*)d_in[2];
  const float* bl   = (const float*)d_in[3];
  const float* Wr   = (const float*)d_in[4];
  const float* br   = (const float*)d_in[5];
  const float* att  = (const float*)d_in[6];
  const float* bias = (const float*)d_in[7];
  const float* gw   = (const float*)d_in[8];
  const float* gb   = (const float*)d_in[9];
  const float* gms  = (const float*)d_in[10];
  int n = in_sizes[0] / 128;
  int E = in_sizes[1] / 2;
  float* outp = (float*)d_out;

  char* w = (char*)d_ws;
  size_t off = 0;
  auto alloc = [&](size_t bytes)->char*{
    char* p = w + off; off += (bytes + 255) & ~(size_t)255; return p;
  };
  unsigned short* xl  = (unsigned short*)alloc((size_t)n*256*2);
  unsigned short* xr  = (unsigned short*)alloc((size_t)n*256*2);
  unsigned short* Wb  = (unsigned short*)alloc(512*128*2);
  float* bcat   = (float*)alloc(512*4);
  int*   counts = (int*)  alloc((size_t)n*4);
  int*   offs   = (int*)  alloc((size_t)n*4);
  int*   cursor = (int*)  alloc((size_t)n*4);
  int*   total  = (int*)  alloc(4);
  int*   ssrc   = (int*)  alloc((size_t)E*4);
  float* colsum = (float*)alloc(128*4);
  float* colsq  = (float*)alloc(128*4);
  float* stats  = (float*)alloc(256*4);
  if (off > ws_size) return;

  hipMemsetAsync(counts, 0, (size_t)n*4, stream);
  hipMemsetAsync(total,  0, 4, stream);
  hipMemsetAsync(colsum, 0, 128*4, stream);
  hipMemsetAsync(colsq,  0, 128*4, stream);

  prep_w       <<<256, 256, 0, stream>>>(Wl, Wr, bl, br, Wb, bcat);
  gemm_mfma    <<<(n+31)/32, 256, 0, stream>>>(x, Wb, bcat, xl, xr, n);
  hist_dst     <<<512, 256, 0, stream>>>(ei, E, counts);
  alloc_offsets<<<(n+255)/256, 256, 0, stream>>>(counts, n, offs, cursor, total);
  scatter_edges<<<512, 256, 0, stream>>>(ei, E, cursor, ssrc);
  node_attn    <<<(n+3)/4, 256, 0, stream>>>(xl, xr, att, bias, offs, counts, ssrc, outp, n);
  col_reduce   <<<512, 256, 0, stream>>>(outp, n, colsum, colsq);
  fin_stats    <<<1, 128, 0, stream>>>(colsum, colsq, gms, stats, n);
  final_ew     <<<2048, 256, 0, stream>>>(outp, x, stats, gw, gb, n);
}